// Round 1
// baseline (141.787 us; speedup 1.0000x reference)
//
#include <hip/hip_runtime.h>
#include <float.h>
#include <math.h>

#define EPS 1e-6f

constexpr int Nn = 8192;   // B*H*W = 8*32*32
constexpr int Dd = 64;
constexpr int Kk = 8192;
constexpr int TN = 128;
constexpr int TK = 128;
constexpr int KSPLIT = 16;
constexpr int KPB = Kk / KSPLIT;          // 512 codewords per block
constexpr int TILES_PER_BLOCK = KPB / TK; // 4

// ---- kernel 1: ||e_k||^2 per codeword ----
__global__ void enorm2_kernel(const float* __restrict__ e, float* __restrict__ en2) {
    int k = blockIdx.x * blockDim.x + threadIdx.x;
    if (k >= Kk) return;
    float s = 0.f;
    #pragma unroll 8
    for (int d = 0; d < Dd; ++d) {
        float v = e[d * Kk + k];
        s += v * v;
    }
    en2[k] = s;
}

// ---- kernel 2: fused distance GEMM + partial argmin ----
// grid (Nn/TN, KSPLIT), block 256. Each block: TN pixels x KPB codewords.
__global__ __launch_bounds__(256) void dist_argmin_kernel(
    const float* __restrict__ x, const float* __restrict__ e,
    const float* __restrict__ en2,
    float* __restrict__ pval, int* __restrict__ pidx)
{
    __shared__ float As[Dd][TN];  // x tile, d-major
    __shared__ float Bs[Dd][TK];  // e tile, d-major

    const int tid = threadIdx.x;
    const int tr = tid >> 4;      // 0..15 row group
    const int tc = tid & 15;      // 0..15 col group

    const int n0 = blockIdx.x * TN;
    const int b = n0 >> 10;        // / (H*W=1024); TN=128 divides 1024
    const int hw0 = n0 & 1023;
    const float* xb = x + b * (Dd * 1024) + hw0;

    // load A tile once (reused across all K-tiles of this block)
    for (int i = tid; i < Dd * TN; i += 256) {
        int d = i >> 7, p = i & 127;
        As[d][p] = xb[d * 1024 + p];
    }

    float bestv[8]; int besti[8];
    #pragma unroll
    for (int r = 0; r < 8; ++r) { bestv[r] = FLT_MAX; besti[r] = 0; }

    const int kbase = blockIdx.y * KPB;
    for (int t = 0; t < TILES_PER_BLOCK; ++t) {
        const int k0 = kbase + t * TK;
        __syncthreads();  // prev iteration done reading Bs (also orders A load at t=0)
        for (int i = tid; i < Dd * TK; i += 256) {
            int d = i >> 7, kk = i & 127;
            Bs[d][kk] = e[d * Kk + k0 + kk];
        }
        __syncthreads();

        float acc[8][8];
        #pragma unroll
        for (int r = 0; r < 8; ++r)
            #pragma unroll
            for (int c = 0; c < 8; ++c) acc[r][c] = 0.f;

        for (int d = 0; d < Dd; ++d) {
            float4 a0 = *(const float4*)&As[d][tr * 8];
            float4 a1 = *(const float4*)&As[d][tr * 8 + 4];
            float4 b0 = *(const float4*)&Bs[d][tc * 8];
            float4 b1 = *(const float4*)&Bs[d][tc * 8 + 4];
            float av[8] = {a0.x,a0.y,a0.z,a0.w,a1.x,a1.y,a1.z,a1.w};
            float bv[8] = {b0.x,b0.y,b0.z,b0.w,b1.x,b1.y,b1.z,b1.w};
            #pragma unroll
            for (int r = 0; r < 8; ++r)
                #pragma unroll
                for (int c = 0; c < 8; ++c)
                    acc[r][c] = fmaf(av[r], bv[c], acc[r][c]);
        }

        // distances (drop constant ||x||^2) + running argmin, ascending k
        #pragma unroll
        for (int c = 0; c < 8; ++c) {
            int kg = k0 + tc * 8 + c;
            float e2 = en2[kg];
            #pragma unroll
            for (int r = 0; r < 8; ++r) {
                float s = e2 - 2.f * acc[r][c];
                if (s < bestv[r]) { bestv[r] = s; besti[r] = kg; }
            }
        }
    }

    // reduce across the 16 tc lanes (same tr group within a wave); idx tiebreak
    #pragma unroll
    for (int m = 1; m < 16; m <<= 1) {
        #pragma unroll
        for (int r = 0; r < 8; ++r) {
            float ov = __shfl_xor(bestv[r], m, 64);
            int   oi = __shfl_xor(besti[r], m, 64);
            if (ov < bestv[r] || (ov == bestv[r] && oi < besti[r])) {
                bestv[r] = ov; besti[r] = oi;
            }
        }
    }
    if (tc == 0) {
        #pragma unroll
        for (int r = 0; r < 8; ++r) {
            int n = n0 + tr * 8 + r;
            pval[n * KSPLIT + blockIdx.y] = bestv[r];
            pidx[n * KSPLIT + blockIdx.y] = besti[r];
        }
    }
}

// ---- kernel 3: final argmin + gather + rotation trick ----
__global__ void finalize_kernel(
    const float* __restrict__ x, const float* __restrict__ e,
    const float* __restrict__ pval, const int* __restrict__ pidx,
    float* __restrict__ out_qd, float* __restrict__ out_q, float* __restrict__ out_ind)
{
    int n = blockIdx.x * blockDim.x + threadIdx.x;
    if (n >= Nn) return;

    float bv = FLT_MAX; int bi = 0;
    for (int s = 0; s < KSPLIT; ++s) {
        float v = pval[n * KSPLIT + s];
        int   i = pidx[n * KSPLIT + s];
        if (v < bv || (v == bv && i < bi)) { bv = v; bi = i; }
    }
    out_ind[n] = (float)bi;

    const int b = n >> 10, hw = n & 1023;
    const float* xb = x + b * (Dd * 1024) + hw;
    const float* eb = e + bi;

    float sx2 = 0.f, sq2 = 0.f, sxq = 0.f;
    #pragma unroll 8
    for (int d = 0; d < Dd; ++d) {
        float xv = xb[d * 1024];
        float qv = eb[d * Kk];
        sx2 = fmaf(xv, xv, sx2);
        sq2 = fmaf(qv, qv, sq2);
        sxq = fmaf(xv, qv, sxq);
    }
    float ne = sqrtf(sx2), nq = sqrtf(sq2);
    float inv_e = 1.f / (ne + EPS), inv_q = 1.f / (nq + EPS);
    float lmbda = (nq + EPS) * inv_e;           // q_norm / e_norm (norms include +EPS)
    float ehat_dot_e = sx2 * inv_e;             // e_hat . e
    float rn2 = sx2 * inv_e * inv_e + 2.f * sxq * inv_e * inv_q + sq2 * inv_q * inv_q;
    float inv_r = rsqrtf(rn2);
    float rde = (sx2 * inv_e + sxq * inv_q) * inv_r;  // r . e (r normalized)

    float* qd_b = out_qd + b * (Dd * 1024) + hw;
    float* q_b  = out_q  + b * (Dd * 1024) + hw;
    #pragma unroll 8
    for (int d = 0; d < Dd; ++d) {
        float xv = xb[d * 1024];
        float qv = eb[d * Kk];
        float rv = (xv * inv_e + qv * inv_q) * inv_r;
        float qh = qv * inv_q;
        qd_b[d * 1024] = lmbda * (xv - 2.f * rv * rde + 2.f * qh * ehat_dot_e);
        q_b[d * 1024]  = qv;
    }
}

extern "C" void kernel_launch(void* const* d_in, const int* in_sizes, int n_in,
                              void* d_out, int out_size, void* d_ws, size_t ws_size,
                              hipStream_t stream) {
    const float* x = (const float*)d_in[0];   // (8,64,32,32)
    const float* e = (const float*)d_in[1];   // (64,8192)
    float* out = (float*)d_out;
    float* out_qd  = out;                  // 524288
    float* out_q   = out + Nn * Dd;        // 524288
    float* out_ind = out + 2 * Nn * Dd;    // 8192 (indices as float values)

    float* en2  = (float*)d_ws;                    // 8192 f32
    float* pval = en2 + Kk;                        // 8192*16 f32
    int*   pidx = (int*)(pval + Nn * KSPLIT);      // 8192*16 i32

    enorm2_kernel<<<Kk / 256, 256, 0, stream>>>(e, en2);
    dist_argmin_kernel<<<dim3(Nn / TN, KSPLIT), 256, 0, stream>>>(x, e, en2, pval, pidx);
    finalize_kernel<<<Nn / 256, 256, 0, stream>>>(x, e, pval, pidx, out_qd, out_q, out_ind);
}